// Round 4
// baseline (252.641 us; speedup 1.0000x reference)
//
#include <hip/hip_runtime.h>
#include <math.h>

// Model: B=32, C=64, T=1024, H=10, OUT=2.
// R19: 64 blocks = 2 per batch (half-t-range each), 512 threads, ONE
// timestep per thread. Parallel phase was issue-bound on 32 CUs at ~88%
// (R18 post-mortem: parallel ~56us, scan ~63us of the 119us kernel);
// spreading to 64 CUs halves per-wave instruction count.
//   S1 embed | S2 bn+tanh + qkv stats | S3 M=KV^T partials (per-batch
//   cross-block combine via ws) | S4 N=M Wc^T/H, prec=q.N | S5 bn+relu ->
//   Iin to ws (agent-scope atomic stores) | S6 LSNN scan on wave 0 of
//   EVEN blocks, reading Iin from global.
// Scan body = R18 (serial fma chain, latency/issue-pinched at ~146
// cyc/step) kept byte-identical; only the row source moved to global.
// Barriers: 5 gbars (S1-stats, S2-stats, M, prec-stats, Iin), count=64.
// Numerics: partial-sum ORDER changes (1e-7 class, same as R18's
// accepted reassociation); spike margins empirically robust.
// Predict: rocprof 119 -> ~95-100us (parallel ~31 + scan ~63).

constexpr int B = 32, C = 64, T = 1024, H = 10;
constexpr int NT = 512;   // threads per block (8 waves)
constexpr int NB = 64;    // 2 blocks per batch element

struct Params {
  const float *beeg, *W_ef, *b_ef, *g_i, *be_i, *Wq, *g_q, *be_q, *Wk, *g_k,
      *be_k, *Wv, *g_v, *be_v, *Wc, *g_c, *be_c, *W_in, *W_rec, *W_cls, *b_cls;
  int* cnt;              // barrier counters (memset 0 each launch)
  double *P1, *P2, *P3;  // cross-block stat partials, layout [ch][64]
  float* PM;             // M partials, layout [100][64]
  float* Iin;            // [B][H][T] scan input
  float* out;
};

// DPP wave64 sum: result valid in lane 63 (VALU pipe, no DS traffic).
template <int CTRL>
__device__ inline float dadd(float v) {
  int x = __builtin_amdgcn_update_dpp(0, __float_as_int(v), CTRL, 0xf, 0xf,
                                      true);
  return v + __int_as_float(x);
}
__device__ inline float wred63(float v) {
  v = dadd<0x111>(v);  // row_shr:1
  v = dadd<0x112>(v);  // row_shr:2
  v = dadd<0x114>(v);  // row_shr:4
  v = dadd<0x118>(v);  // row_shr:8
  v = dadd<0x142>(v);  // row_bcast:15
  v = dadd<0x143>(v);  // row_bcast:31
  return v;            // lane 63 = full sum
}

// 64-block barrier, fence-free (all cross-block data via agent-scope atomics).
__device__ inline void gbar(int* cnt, int phase, int tid) {
  __syncthreads();
  if (tid == 0) {
    __hip_atomic_fetch_add(&cnt[phase], 1, __ATOMIC_RELEASE,
                           __HIP_MEMORY_SCOPE_AGENT);
    while (__hip_atomic_load(&cnt[phase], __ATOMIC_RELAXED,
                             __HIP_MEMORY_SCOPE_AGENT) < NB)
      __builtin_amdgcn_s_sleep(2);
  }
  __syncthreads();
}

__global__ void __launch_bounds__(NT) fused13(Params p) {
  const int blk = blockIdx.x;
  const int b = blk >> 1, half = blk & 1;
  const int tid = threadIdx.x;
  const int lane = tid & 63, wid = tid >> 6;   // 8 waves
  const int t = half * NT + tid;               // this thread's timestep

  __shared__ float swred[8 * 60];
  __shared__ float mpw[8 * 100];
  __shared__ __align__(16) float gtab[T];
  __shared__ double dred2[60 * 17 + 4];        // combine partials (pad 17)
  __shared__ double dtot[60];
  __shared__ float stM[30], stI[30], Ms[100], Nl[100];

  // g[t] = (9(1-0.9^{T-t}) - 4(1-0.8^{T-t})) / T  (f32 closed form)
  {
    const float L2A = -0.15200309344504995f;   // log2(0.9)
    const float L2D = -0.32192809488736235f;   // log2(0.8)
    float m0 = (float)(T - tid), m1 = (float)(T - (tid + NT));
    gtab[tid] = (9.0f * (1.0f - exp2f(m0 * L2A)) -
                 4.0f * (1.0f - exp2f(m0 * L2D))) * (1.0f / (float)T);
    gtab[tid + NT] = (9.0f * (1.0f - exp2f(m1 * L2A)) -
                      4.0f * (1.0f - exp2f(m1 * L2D))) * (1.0f / (float)T);
  }

  // parallel stats combine: P layout [ch][64]; ch x 16 workers, 4 loads each.
  auto combine = [&](double* P, int Q2) {
    for (int id = tid; id < Q2 * 16; id += NT) {
      int ch = id >> 4, i = id & 15;
      double s = __hip_atomic_load(&P[ch * 64 + i], __ATOMIC_RELAXED,
                                   __HIP_MEMORY_SCOPE_AGENT) +
                 __hip_atomic_load(&P[ch * 64 + 16 + i], __ATOMIC_RELAXED,
                                   __HIP_MEMORY_SCOPE_AGENT) +
                 __hip_atomic_load(&P[ch * 64 + 32 + i], __ATOMIC_RELAXED,
                                   __HIP_MEMORY_SCOPE_AGENT) +
                 __hip_atomic_load(&P[ch * 64 + 48 + i], __ATOMIC_RELAXED,
                                   __HIP_MEMORY_SCOPE_AGENT);
      dred2[ch * 17 + i] = s;
    }
    __syncthreads();
    if (tid < Q2) {
      double s = 0.0;
#pragma unroll
      for (int i = 0; i < 16; ++i) s += dred2[tid * 17 + i];
      dtot[tid] = s;
    }
    __syncthreads();
  };

  // ---------------- S1: embed (weights via uniform/scalar loads)
  float p1[H];
#pragma unroll
  for (int h = 0; h < H; ++h) p1[h] = p.b_ef[h];
  {
    const float* bp = p.beeg + (size_t)b * C * T;
#pragma unroll 8
    for (int c = 0; c < C; ++c) {
      float v = bp[(size_t)c * T + t];
#pragma unroll
      for (int h = 0; h < H; ++h)
        p1[h] = fmaf(v, p.W_ef[h * C + c], p1[h]);   // wave-uniform weight
    }
  }
#pragma unroll
  for (int h = 0; h < H; ++h) {
    float r1 = wred63(p1[h]);
    float r2 = wred63(p1[h] * p1[h]);
    if (lane == 63) { swred[wid * 60 + h] = r1; swred[wid * 60 + 10 + h] = r2; }
  }
  __syncthreads();
  if (tid < 20) {
    float s = 0.f;
#pragma unroll
    for (int w = 0; w < 8; ++w) s += swred[w * 60 + tid];
    __hip_atomic_store(&p.P1[tid * 64 + blk], (double)s, __ATOMIC_RELAXED,
                       __HIP_MEMORY_SCOPE_AGENT);
  }
  gbar(p.cnt, 0, tid);
  combine(p.P1, 20);
  if (tid < 10) {
    double mean = dtot[tid] * (1.0 / 32768.0);
    double var  = dtot[10 + tid] * (1.0 / 32768.0) - mean * mean;
    stM[tid] = (float)mean;
    stI[tid] = (float)(1.0 / sqrt(var + 1e-5));
  }
  __syncthreads();

  // ---------------- S2: x = tanh(bn(pre1)); qkv stats (accumulators only)
  float xa[H];
#pragma unroll
  for (int j = 0; j < H; ++j)
    xa[j] = tanhf(p.g_i[j] * (p1[j] - stM[j]) * stI[j] + p.be_i[j]);
#pragma unroll
  for (int h = 0; h < H; ++h) {
    float qa = 0.f, ka = 0.f, va = 0.f;
#pragma unroll
    for (int j = 0; j < H; ++j) {
      qa = fmaf(xa[j], p.Wq[h * H + j], qa);
      ka = fmaf(xa[j], p.Wk[h * H + j], ka);
      va = fmaf(xa[j], p.Wv[h * H + j], va);
    }
    float r1 = wred63(qa), r2 = wred63(qa * qa);
    float r3 = wred63(ka), r4 = wred63(ka * ka);
    float r5 = wred63(va), r6 = wred63(va * va);
    if (lane == 63) {
      swred[wid * 60 + h]      = r1; swred[wid * 60 + 30 + h] = r2;
      swred[wid * 60 + 10 + h] = r3; swred[wid * 60 + 40 + h] = r4;
      swred[wid * 60 + 20 + h] = r5; swred[wid * 60 + 50 + h] = r6;
    }
  }
  __syncthreads();
  if (tid < 60) {
    float s = 0.f;
#pragma unroll
    for (int w = 0; w < 8; ++w) s += swred[w * 60 + tid];
    __hip_atomic_store(&p.P2[tid * 64 + blk], (double)s, __ATOMIC_RELAXED,
                       __HIP_MEMORY_SCOPE_AGENT);
  }
  gbar(p.cnt, 1, tid);
  combine(p.P2, 60);
  if (tid < 30) {
    double mean = dtot[tid] * (1.0 / 32768.0);
    double var  = dtot[30 + tid] * (1.0 / 32768.0) - mean * mean;
    stM[tid] = (float)mean;
    stI[tid] = (float)(1.0 / sqrt(var + 1e-5));
  }
  __syncthreads();

  // ---------------- S3: M = KV^T partials (per-batch, cross-block via ws)
  {
    float kx[H], vx[H];
#pragma unroll
    for (int h = 0; h < H; ++h) {
      float ka = 0.f, va = 0.f;
#pragma unroll
      for (int j = 0; j < H; ++j) {
        ka = fmaf(xa[j], p.Wk[h * H + j], ka);
        va = fmaf(xa[j], p.Wv[h * H + j], va);
      }
      kx[h] = fmaxf(p.g_k[h] * (ka - stM[10 + h]) * stI[10 + h] + p.be_k[h], 0.f);
      vx[h] = tanhf(p.g_v[h] * (va - stM[20 + h]) * stI[20 + h] + p.be_v[h]);
    }
#pragma unroll
    for (int i = 0; i < H; ++i)
#pragma unroll
      for (int j = 0; j < H; ++j) {
        float r = wred63(kx[i] * vx[j]);
        if (lane == 63) mpw[wid * 100 + i * 10 + j] = r;
      }
  }
  __syncthreads();
  if (tid < 100) {
    float s = 0.f;
#pragma unroll
    for (int w = 0; w < 8; ++w) s += mpw[w * 100 + tid];
    __hip_atomic_store(&p.PM[tid * 64 + blk], s, __ATOMIC_RELAXED,
                       __HIP_MEMORY_SCOPE_AGENT);
  }
  gbar(p.cnt, 2, tid);
  if (tid < 100) {
    // both halves of batch b sum the same pair in the same order
    float s = __hip_atomic_load(&p.PM[tid * 64 + 2 * b], __ATOMIC_RELAXED,
                                __HIP_MEMORY_SCOPE_AGENT) +
              __hip_atomic_load(&p.PM[tid * 64 + 2 * b + 1], __ATOMIC_RELAXED,
                                __HIP_MEMORY_SCOPE_AGENT);
    Ms[tid] = s;
  }
  __syncthreads();

  // ---------------- S4: N = (M Wc^T)/H; recompute q; prec = q . N
  if (tid < 100) {
    int i = tid / 10, h = tid % 10;
    float a = 0.f;
#pragma unroll
    for (int j = 0; j < H; ++j) a = fmaf(Ms[i * 10 + j], p.Wc[h * H + j], a);
    Nl[tid] = a * 0.1f;
  }
  __syncthreads();
  float pca[H];
  {
    float qv[H];
#pragma unroll
    for (int h = 0; h < H; ++h) {
      float qa = 0.f;
#pragma unroll
      for (int j = 0; j < H; ++j) qa = fmaf(xa[j], p.Wq[h * H + j], qa);
      qv[h] = fmaxf(p.g_q[h] * (qa - stM[h]) * stI[h] + p.be_q[h], 0.f);
    }
#pragma unroll
    for (int h = 0; h < H; ++h) {
      float a = 0.f;
#pragma unroll
      for (int i = 0; i < H; ++i) a = fmaf(qv[i], Nl[i * 10 + h], a);
      pca[h] = a;
    }
  }
#pragma unroll
  for (int h = 0; h < H; ++h) {
    float r1 = wred63(pca[h]);
    float r2 = wred63(pca[h] * pca[h]);
    if (lane == 63) { swred[wid * 60 + h] = r1; swred[wid * 60 + 10 + h] = r2; }
  }
  __syncthreads();
  if (tid < 20) {
    float s = 0.f;
#pragma unroll
    for (int w = 0; w < 8; ++w) s += swred[w * 60 + tid];
    __hip_atomic_store(&p.P3[tid * 64 + blk], (double)s, __ATOMIC_RELAXED,
                       __HIP_MEMORY_SCOPE_AGENT);
  }
  gbar(p.cnt, 3, tid);
  combine(p.P3, 20);
  if (tid < 10) {
    double mean = dtot[tid] * (1.0 / 32768.0);
    double var  = dtot[10 + tid] * (1.0 / 32768.0) - mean * mean;
    stM[tid] = (float)mean;
    stI[tid] = (float)(1.0 / sqrt(var + 1e-5));
  }
  __syncthreads();

  // ---------------- S5: bn+relu, Iin -> ws (agent-scope stores; drained by
  // the wave's vmcnt at gbar's __syncthreads, visible at LLC before arrival)
  {
    float ca[H];
#pragma unroll
    for (int j = 0; j < H; ++j)
      ca[j] = fmaxf(p.g_c[j] * (pca[j] - stM[j]) * stI[j] + p.be_c[j], 0.f);
#pragma unroll
    for (int h = 0; h < H; ++h) {
      float a = 0.f;
#pragma unroll
      for (int j = 0; j < H; ++j) a = fmaf(ca[j], p.W_in[h * H + j], a);
      __hip_atomic_store(&p.Iin[(size_t)b * (H * T) + h * T + t], a,
                         __ATOMIC_RELAXED, __HIP_MEMORY_SCOPE_AGENT);
    }
  }
  gbar(p.cnt, 4, tid);

  // ---------------- S6: LSNN scan, wave 0 of EVEN blocks; R18 body,
  // row source = global ws (reader cache-cold for the odd half -> fresh).
  if (half == 0 && tid < 64) {
    // gtot closed form: .9^1024/.8^1024 underflow -> (5*1024 - 81 + 16)/1024
    const float gtot = 4.9365234375f;

    const int slot = lane < H ? lane : 0;   // inactive lanes broadcast row 0
    const float* row = p.Iin + (size_t)b * (H * T) + (size_t)slot * T;
    float wrf[H];                           // W_rec row (this lane's neuron)
#pragma unroll
    for (int j = 0; j < H; ++j)
      wrf[j] = (lane < H) ? p.W_rec[lane * H + j] : 0.f;

    float cur = 0.f, vm = 0.f, S = 0.f;
    float zf = 0.f;   // prev-step spike, per-lane float (lane j holds z_j)

    auto step = [&](float iin, float gt) {
      float acc = cur + iin;
#pragma unroll
      for (int j = 0; j < H; ++j) {
        float zj = __int_as_float(
            __builtin_amdgcn_readlane(__float_as_int(zf), j));
        acc = fmaf(zj, wrf[j], acc);
      }
      float v_dec = fmaf(0.1f, acc - vm, vm);  // vm + 0.1*(i_jump - vm)
      cur = 0.8f * acc;                        // i_dec
      bool z = v_dec > 0.5f;
      vm = z ? 0.f : v_dec;
      zf = z ? 1.0f : 0.0f;
      S = fmaf(zf, gt, S);                     // exact: +gt or +0.0
    };

    float4 iA = *(const float4*)&row[0];
    float4 iB = *(const float4*)&row[4];
    float4 gA = *(const float4*)&gtab[0], gB = *(const float4*)&gtab[4];

    for (int t8 = 0; t8 < T - 8; t8 += 8) {
      float4 iN1 = *(const float4*)&row[t8 + 8];
      float4 iN2 = *(const float4*)&row[t8 + 12];
      float4 gN1 = *(const float4*)&gtab[t8 + 8];
      float4 gN2 = *(const float4*)&gtab[t8 + 12];
      step(iA.x, gA.x); step(iA.y, gA.y); step(iA.z, gA.z); step(iA.w, gA.w);
      step(iB.x, gB.x); step(iB.y, gB.y); step(iB.z, gB.z); step(iB.w, gB.w);
      iA = iN1; iB = iN2; gA = gN1; gB = gN2;
    }
    step(iA.x, gA.x); step(iA.y, gA.y); step(iA.z, gA.z); step(iA.w, gA.w);
    step(iB.x, gB.x); step(iB.y, gB.y); step(iB.z, gB.z); step(iB.w, gB.w);

    int li = lane < H ? lane : 0;
    float c0 = (lane < H) ? S * p.W_cls[li]     : 0.f;
    float c1 = (lane < H) ? S * p.W_cls[H + li] : 0.f;
    float r0 = wred63(c0), r1 = wred63(c1);
    if (lane == 63) {
      p.out[b * 2 + 0] = r0 + gtot * p.b_cls[0];
      p.out[b * 2 + 1] = r1 + gtot * p.b_cls[1];
    }
  }
}

extern "C" void kernel_launch(void* const* d_in, const int* in_sizes, int n_in,
                              void* d_out, int out_size, void* d_ws, size_t ws_size,
                              hipStream_t stream) {
  Params p;
  p.beeg  = (const float*)d_in[2];
  p.W_ef  = (const float*)d_in[4];
  p.b_ef  = (const float*)d_in[5];
  p.g_i   = (const float*)d_in[6];
  p.be_i  = (const float*)d_in[7];
  p.Wq    = (const float*)d_in[8];
  p.g_q   = (const float*)d_in[9];
  p.be_q  = (const float*)d_in[10];
  p.Wk    = (const float*)d_in[11];
  p.g_k   = (const float*)d_in[12];
  p.be_k  = (const float*)d_in[13];
  p.Wv    = (const float*)d_in[14];
  p.g_v   = (const float*)d_in[15];
  p.be_v  = (const float*)d_in[16];
  p.Wc    = (const float*)d_in[17];
  p.g_c   = (const float*)d_in[18];
  p.be_c  = (const float*)d_in[19];
  p.W_in  = (const float*)d_in[20];
  p.W_rec = (const float*)d_in[21];
  p.W_cls = (const float*)d_in[22];
  p.b_cls = (const float*)d_in[23];

  char* ws = (char*)d_ws;
  p.cnt = (int*)ws;                       // 5 counters, memset below
  p.P1  = (double*)(ws + 256);            // [20][64] doubles = 10240 B
  p.P2  = (double*)(ws + 256 + 10240);    // [60][64] doubles = 30720 B
  p.P3  = (double*)(ws + 256 + 40960);    // [20][64] doubles = 10240 B
  p.PM  = (float*)(ws + 256 + 51200);     // [100][64] floats = 25600 B
  p.Iin = (float*)(ws + 77056);           // [32][10][1024] f32 = 1310720 B
  p.out = (float*)d_out;

  (void)hipMemsetAsync(d_ws, 0, 256, stream);  // zero barrier counters
  fused13<<<dim3(NB), dim3(NT), 0, stream>>>(p);
}

// Round 5
// 237.344 us; speedup vs baseline: 1.0645x; 1.0645x over previous
//
#include <hip/hip_runtime.h>
#include <math.h>

// Model: B=32, C=64, T=1024, H=10, OUT=2.
// R19 post-mortem: REGRESSION 119->150.6us. (a) global-sourced scan +36us
// (single wave can't hide vmem stalls) -> scan input must stay in LDS.
// (b) 2x CUs bought only -5us on the parallel phase + VALUBusy ~3% ->
// parallel is LATENCY-bound at 2 waves/SIMD, not issue-bound.
// R20: back to 32 blocks / 3 gbars / LDS scan, but NT=1024 (16 waves,
// ONE timestep per thread) with __launch_bounds__(1024,4): 128 VGPR ->
// 4 waves/SIMD = 2x latency-hiding on the same CU. S3 becomes single-pass
// (halves wred63 count there). LDS unchanged 58.9KB (swred/mpw alias slab).
// Scan = R18 body, fma chain split into two 5-chains (latency 146->~125
// cyc/step; same reassociation class R18 proved keeps absmax 0.0).
// Predict: parallel ~55->~30, scan 63->~57, rocprof 119 -> ~85-95us.

constexpr int B = 32, C = 64, T = 1024, H = 10;
constexpr int NT = 1024;  // threads per block (16 waves), 1 timestep/thread
constexpr int RS = 1028;  // scan-row stride (floats): 16B-aligned

struct Params {
  const float *beeg, *W_ef, *b_ef, *g_i, *be_i, *Wq, *g_q, *be_q, *Wk, *g_k,
      *be_k, *Wv, *g_v, *be_v, *Wc, *g_c, *be_c, *W_in, *W_rec, *W_cls, *b_cls;
  int* cnt;              // barrier counters (memset 0 each launch)
  double *P1, *P2, *P3;  // cross-block stat partials, layout [ch][32]
  float* out;
};

// DPP wave64 sum: result valid in lane 63 (VALU pipe, no DS traffic).
template <int CTRL>
__device__ inline float dadd(float v) {
  int x = __builtin_amdgcn_update_dpp(0, __float_as_int(v), CTRL, 0xf, 0xf,
                                      true);
  return v + __int_as_float(x);
}
__device__ inline float wred63(float v) {
  v = dadd<0x111>(v);  // row_shr:1
  v = dadd<0x112>(v);  // row_shr:2
  v = dadd<0x114>(v);  // row_shr:4
  v = dadd<0x118>(v);  // row_shr:8
  v = dadd<0x142>(v);  // row_bcast:15
  v = dadd<0x143>(v);  // row_bcast:31
  return v;            // lane 63 = full sum
}

// 32-block barrier, fence-free (all cross-block data via agent-scope atomics).
__device__ inline void gbar(int* cnt, int phase, int tid) {
  __syncthreads();
  if (tid == 0) {
    __hip_atomic_fetch_add(&cnt[phase], 1, __ATOMIC_RELEASE,
                           __HIP_MEMORY_SCOPE_AGENT);
    while (__hip_atomic_load(&cnt[phase], __ATOMIC_RELAXED,
                             __HIP_MEMORY_SCOPE_AGENT) < B)
      __builtin_amdgcn_s_sleep(2);
  }
  __syncthreads();
}

__global__ void __launch_bounds__(NT, 4) fused14(Params p) {
  const int b = blockIdx.x, tid = threadIdx.x;
  const int lane = tid & 63, wid = tid >> 6;   // 16 waves

  __shared__ __align__(16) float slab[T * 11];   // scratch, then Iin [h][RS]
  __shared__ __align__(16) float gtab[T];        // 4KB
  __shared__ double dred2[60 * 17 + 4];          // combine partials (pad 17)
  __shared__ double dtot[60];
  __shared__ float stM[30], stI[30], Ms[100], Nl[100];

  float* swred = slab;          // [16][60] stats scratch (dead before S5)
  float* mpw   = slab + 1024;   // [16][100] M partials (dead before S5)

  // g[t] = (9(1-0.9^{T-t}) - 4(1-0.8^{T-t})) / T  (f32 closed form)
  {
    const float L2A = -0.15200309344504995f;   // log2(0.9)
    const float L2D = -0.32192809488736235f;   // log2(0.8)
    float m0 = (float)(T - tid);
    gtab[tid] = (9.0f * (1.0f - exp2f(m0 * L2A)) -
                 4.0f * (1.0f - exp2f(m0 * L2D))) * (1.0f / (float)T);
  }

  // parallel stats combine: P layout [ch][32]; ch x 16 workers, 2 loads each.
  auto combine = [&](double* P, int Q2) {
    for (int id = tid; id < Q2 * 16; id += NT) {
      int ch = id >> 4, i = id & 15;
      double s = __hip_atomic_load(&P[ch * 32 + i], __ATOMIC_RELAXED,
                                   __HIP_MEMORY_SCOPE_AGENT) +
                 __hip_atomic_load(&P[ch * 32 + 16 + i], __ATOMIC_RELAXED,
                                   __HIP_MEMORY_SCOPE_AGENT);
      dred2[ch * 17 + i] = s;
    }
    __syncthreads();
    if (tid < Q2) {
      double s = 0.0;
#pragma unroll
      for (int i = 0; i < 16; ++i) s += dred2[tid * 17 + i];
      dtot[tid] = s;
    }
    __syncthreads();
  };

  // ---------------- S1: embed (weights via uniform/scalar loads)
  float p1[H];
#pragma unroll
  for (int h = 0; h < H; ++h) p1[h] = p.b_ef[h];
  {
    const float* bp = p.beeg + (size_t)b * C * T;
#pragma unroll 8
    for (int c = 0; c < C; ++c) {
      float v = bp[(size_t)c * T + tid];
#pragma unroll
      for (int h = 0; h < H; ++h)
        p1[h] = fmaf(v, p.W_ef[h * C + c], p1[h]);   // wave-uniform weight
    }
  }
#pragma unroll
  for (int h = 0; h < H; ++h) {
    float r1 = wred63(p1[h]);
    float r2 = wred63(p1[h] * p1[h]);
    if (lane == 63) { swred[wid * 60 + h] = r1; swred[wid * 60 + 10 + h] = r2; }
  }
  __syncthreads();
  if (tid < 20) {
    float s = 0.f;
#pragma unroll
    for (int w = 0; w < 16; ++w) s += swred[w * 60 + tid];
    __hip_atomic_store(&p.P1[tid * 32 + b], (double)s, __ATOMIC_RELAXED,
                       __HIP_MEMORY_SCOPE_AGENT);
  }
  gbar(p.cnt, 0, tid);
  combine(p.P1, 20);
  if (tid < 10) {
    double mean = dtot[tid] * (1.0 / 32768.0);
    double var  = dtot[10 + tid] * (1.0 / 32768.0) - mean * mean;
    stM[tid] = (float)mean;
    stI[tid] = (float)(1.0 / sqrt(var + 1e-5));
  }
  __syncthreads();

  // ---------------- S2: x = tanh(bn(pre1)); qkv stats (accumulators only)
  float xa[H];
#pragma unroll
  for (int j = 0; j < H; ++j)
    xa[j] = tanhf(p.g_i[j] * (p1[j] - stM[j]) * stI[j] + p.be_i[j]);
#pragma unroll
  for (int h = 0; h < H; ++h) {
    float qa = 0.f, ka = 0.f, va = 0.f;
#pragma unroll
    for (int j = 0; j < H; ++j) {
      qa = fmaf(xa[j], p.Wq[h * H + j], qa);
      ka = fmaf(xa[j], p.Wk[h * H + j], ka);
      va = fmaf(xa[j], p.Wv[h * H + j], va);
    }
    float r1 = wred63(qa), r2 = wred63(qa * qa);
    float r3 = wred63(ka), r4 = wred63(ka * ka);
    float r5 = wred63(va), r6 = wred63(va * va);
    if (lane == 63) {
      swred[wid * 60 + h]      = r1; swred[wid * 60 + 30 + h] = r2;
      swred[wid * 60 + 10 + h] = r3; swred[wid * 60 + 40 + h] = r4;
      swred[wid * 60 + 20 + h] = r5; swred[wid * 60 + 50 + h] = r6;
    }
  }
  __syncthreads();
  if (tid < 60) {
    float s = 0.f;
#pragma unroll
    for (int w = 0; w < 16; ++w) s += swred[w * 60 + tid];
    __hip_atomic_store(&p.P2[tid * 32 + b], (double)s, __ATOMIC_RELAXED,
                       __HIP_MEMORY_SCOPE_AGENT);
  }
  gbar(p.cnt, 1, tid);
  combine(p.P2, 60);
  if (tid < 30) {
    double mean = dtot[tid] * (1.0 / 32768.0);
    double var  = dtot[30 + tid] * (1.0 / 32768.0) - mean * mean;
    stM[tid] = (float)mean;
    stI[tid] = (float)(1.0 / sqrt(var + 1e-5));
  }
  __syncthreads();

  // ---------------- S3: M = KV^T, single pass (one timestep per thread)
  {
    float kx[H], vx[H];
#pragma unroll
    for (int h = 0; h < H; ++h) {
      float ka = 0.f, va = 0.f;
#pragma unroll
      for (int j = 0; j < H; ++j) {
        ka = fmaf(xa[j], p.Wk[h * H + j], ka);
        va = fmaf(xa[j], p.Wv[h * H + j], va);
      }
      kx[h] = fmaxf(p.g_k[h] * (ka - stM[10 + h]) * stI[10 + h] + p.be_k[h], 0.f);
      vx[h] = tanhf(p.g_v[h] * (va - stM[20 + h]) * stI[20 + h] + p.be_v[h]);
    }
#pragma unroll
    for (int i = 0; i < H; ++i)
#pragma unroll
      for (int j = 0; j < H; ++j) {
        float r = wred63(kx[i] * vx[j]);
        if (lane == 63) mpw[wid * 100 + i * 10 + j] = r;
      }
  }
  __syncthreads();
  if (tid < 100) {
    float s = 0.f;
#pragma unroll
    for (int w = 0; w < 16; ++w) s += mpw[w * 100 + tid];
    Ms[tid] = s;
  }
  __syncthreads();

  // ---------------- S4: N = (M Wc^T)/H; recompute q; prec = q . N
  if (tid < 100) {
    int i = tid / 10, h = tid % 10;
    float a = 0.f;
#pragma unroll
    for (int j = 0; j < H; ++j) a = fmaf(Ms[i * 10 + j], p.Wc[h * H + j], a);
    Nl[tid] = a * 0.1f;
  }
  __syncthreads();
  float pca[H];
  {
    float qv[H];
#pragma unroll
    for (int h = 0; h < H; ++h) {
      float qa = 0.f;
#pragma unroll
      for (int j = 0; j < H; ++j) qa = fmaf(xa[j], p.Wq[h * H + j], qa);
      qv[h] = fmaxf(p.g_q[h] * (qa - stM[h]) * stI[h] + p.be_q[h], 0.f);
    }
#pragma unroll
    for (int h = 0; h < H; ++h) {
      float a = 0.f;
#pragma unroll
      for (int i = 0; i < H; ++i) a = fmaf(qv[i], Nl[i * 10 + h], a);
      pca[h] = a;
    }
  }
#pragma unroll
  for (int h = 0; h < H; ++h) {
    float r1 = wred63(pca[h]);
    float r2 = wred63(pca[h] * pca[h]);
    if (lane == 63) { swred[wid * 60 + h] = r1; swred[wid * 60 + 10 + h] = r2; }
  }
  __syncthreads();
  if (tid < 20) {
    float s = 0.f;
#pragma unroll
    for (int w = 0; w < 16; ++w) s += swred[w * 60 + tid];
    __hip_atomic_store(&p.P3[tid * 32 + b], (double)s, __ATOMIC_RELAXED,
                       __HIP_MEMORY_SCOPE_AGENT);
  }
  gbar(p.cnt, 2, tid);
  combine(p.P3, 20);
  if (tid < 10) {
    double mean = dtot[tid] * (1.0 / 32768.0);
    double var  = dtot[10 + tid] * (1.0 / 32768.0) - mean * mean;
    stM[tid] = (float)mean;
    stI[tid] = (float)(1.0 / sqrt(var + 1e-5));
  }
  __syncthreads();   // all slab-scratch reads done before S5 overwrites

  // ---------------- S5: bn+relu, Iin into LDS rows [h][RS]
  {
    float ca[H];
#pragma unroll
    for (int j = 0; j < H; ++j)
      ca[j] = fmaxf(p.g_c[j] * (pca[j] - stM[j]) * stI[j] + p.be_c[j], 0.f);
#pragma unroll
    for (int h = 0; h < H; ++h) {
      float a = 0.f;
#pragma unroll
      for (int j = 0; j < H; ++j) a = fmaf(ca[j], p.W_in[h * H + j], a);
      slab[h * RS + tid] = a;
    }
  }
  __syncthreads();

  // ---------------- S6: LSNN scan, wave 0 only; readlane + dual fma chains
  if (tid < 64) {
    // gtot closed form: .9^1024/.8^1024 underflow -> (5*1024 - 81 + 16)/1024
    const float gtot = 4.9365234375f;

    const int slot = lane < H ? lane : 0;   // inactive lanes broadcast row 0
    const float* row = slab + slot * RS;
    float wrf[H];                           // W_rec row (this lane's neuron)
#pragma unroll
    for (int j = 0; j < H; ++j)
      wrf[j] = (lane < H) ? p.W_rec[lane * H + j] : 0.f;

    float cur = 0.f, vm = 0.f, S = 0.f;
    float zf = 0.f;   // prev-step spike, per-lane float (lane j holds z_j)

    auto step = [&](float iin, float gt) {
      // i_jump = cur + iin + sum_j z_j*w_j as TWO parallel fma chains
      // (even/odd j) + one add: products exact (z in {0,1}); association
      // order change only (same class as R18's accepted reassociation).
      float zj[H];
#pragma unroll
      for (int j = 0; j < H; ++j)
        zj[j] = __int_as_float(
            __builtin_amdgcn_readlane(__float_as_int(zf), j));
      float acc0 = cur + iin;
      float acc1 = 0.f;
#pragma unroll
      for (int j = 0; j < H; j += 2) {
        acc0 = fmaf(zj[j],     wrf[j],     acc0);
        acc1 = fmaf(zj[j + 1], wrf[j + 1], acc1);
      }
      float acc = acc0 + acc1;
      float v_dec = fmaf(0.1f, acc - vm, vm);  // vm + 0.1*(i_jump - vm)
      cur = 0.8f * acc;                        // i_dec
      bool z = v_dec > 0.5f;
      vm = z ? 0.f : v_dec;
      zf = z ? 1.0f : 0.0f;
      S = fmaf(zf, gt, S);                     // exact: +gt or +0.0
    };

    float4 iA = *(const float4*)&row[0];
    float4 iB = *(const float4*)&row[4];
    float4 gA = *(const float4*)&gtab[0], gB = *(const float4*)&gtab[4];

    for (int t8 = 0; t8 < T - 8; t8 += 8) {
      float4 iN1 = *(const float4*)&row[t8 + 8];
      float4 iN2 = *(const float4*)&row[t8 + 12];
      float4 gN1 = *(const float4*)&gtab[t8 + 8];
      float4 gN2 = *(const float4*)&gtab[t8 + 12];
      step(iA.x, gA.x); step(iA.y, gA.y); step(iA.z, gA.z); step(iA.w, gA.w);
      step(iB.x, gB.x); step(iB.y, gB.y); step(iB.z, gB.z); step(iB.w, gB.w);
      iA = iN1; iB = iN2; gA = gN1; gB = gN2;
    }
    step(iA.x, gA.x); step(iA.y, gA.y); step(iA.z, gA.z); step(iA.w, gA.w);
    step(iB.x, gB.x); step(iB.y, gB.y); step(iB.z, gB.z); step(iB.w, gB.w);

    int li = lane < H ? lane : 0;
    float c0 = (lane < H) ? S * p.W_cls[li]     : 0.f;
    float c1 = (lane < H) ? S * p.W_cls[H + li] : 0.f;
    float r0 = wred63(c0), r1 = wred63(c1);
    if (lane == 63) {
      p.out[b * 2 + 0] = r0 + gtot * p.b_cls[0];
      p.out[b * 2 + 1] = r1 + gtot * p.b_cls[1];
    }
  }
}

extern "C" void kernel_launch(void* const* d_in, const int* in_sizes, int n_in,
                              void* d_out, int out_size, void* d_ws, size_t ws_size,
                              hipStream_t stream) {
  Params p;
  p.beeg  = (const float*)d_in[2];
  p.W_ef  = (const float*)d_in[4];
  p.b_ef  = (const float*)d_in[5];
  p.g_i   = (const float*)d_in[6];
  p.be_i  = (const float*)d_in[7];
  p.Wq    = (const float*)d_in[8];
  p.g_q   = (const float*)d_in[9];
  p.be_q  = (const float*)d_in[10];
  p.Wk    = (const float*)d_in[11];
  p.g_k   = (const float*)d_in[12];
  p.be_k  = (const float*)d_in[13];
  p.Wv    = (const float*)d_in[14];
  p.g_v   = (const float*)d_in[15];
  p.be_v  = (const float*)d_in[16];
  p.Wc    = (const float*)d_in[17];
  p.g_c   = (const float*)d_in[18];
  p.be_c  = (const float*)d_in[19];
  p.W_in  = (const float*)d_in[20];
  p.W_rec = (const float*)d_in[21];
  p.W_cls = (const float*)d_in[22];
  p.b_cls = (const float*)d_in[23];

  char* ws = (char*)d_ws;
  p.cnt = (int*)ws;                            // 3 counters, memset below
  p.P1  = (double*)(ws + 256);                 // [20][32] doubles
  p.P2  = (double*)(ws + 256 + 5120);          // [60][32] doubles
  p.P3  = (double*)(ws + 256 + 5120 + 15360);  // [20][32] doubles
  p.out = (float*)d_out;

  (void)hipMemsetAsync(d_ws, 0, 256, stream);  // zero barrier counters
  fused14<<<dim3(B), dim3(NT), 0, stream>>>(p);
}

// Round 6
// 235.287 us; speedup vs baseline: 1.0738x; 1.0087x over previous
//
#include <hip/hip_runtime.h>
#include <math.h>

// Model: B=32, C=64, T=1024, H=10, OUT=2.
// R20 post-mortem: REGRESSION 119->139us was a TOOLING bug, not theory:
// __launch_bounds__(1024, 4)'s 2nd arg acted as min-WORKGROUPS/CU
// (CUDA semantics) -> 64 waves/CU target -> 64-VGPR budget -> scratch
// spills (WRITE_SIZE 104KB->9.3MB, FETCH 4.75->9.0MB = spill traffic).
// The 16-wave structure was never tested at its intended 128-VGPR point.
// R21: IDENTICAL kernel, __launch_bounds__(1024) only. A 16-wave block
// must be launchable -> compiler caps VGPR at 128 (4 waves/SIMD), no
// spills. Clean A/B on register budget.
// Predict: VGPR 64->128, WRITE ~104KB, FETCH ~4.75MB, dur 139 -> ~85-100us
// (parallel ~30-40 at 4 waves/SIMD + scan ~57). absmax 0.

constexpr int B = 32, C = 64, T = 1024, H = 10;
constexpr int NT = 1024;  // threads per block (16 waves), 1 timestep/thread
constexpr int RS = 1028;  // scan-row stride (floats): 16B-aligned

struct Params {
  const float *beeg, *W_ef, *b_ef, *g_i, *be_i, *Wq, *g_q, *be_q, *Wk, *g_k,
      *be_k, *Wv, *g_v, *be_v, *Wc, *g_c, *be_c, *W_in, *W_rec, *W_cls, *b_cls;
  int* cnt;              // barrier counters (memset 0 each launch)
  double *P1, *P2, *P3;  // cross-block stat partials, layout [ch][32]
  float* out;
};

// DPP wave64 sum: result valid in lane 63 (VALU pipe, no DS traffic).
template <int CTRL>
__device__ inline float dadd(float v) {
  int x = __builtin_amdgcn_update_dpp(0, __float_as_int(v), CTRL, 0xf, 0xf,
                                      true);
  return v + __int_as_float(x);
}
__device__ inline float wred63(float v) {
  v = dadd<0x111>(v);  // row_shr:1
  v = dadd<0x112>(v);  // row_shr:2
  v = dadd<0x114>(v);  // row_shr:4
  v = dadd<0x118>(v);  // row_shr:8
  v = dadd<0x142>(v);  // row_bcast:15
  v = dadd<0x143>(v);  // row_bcast:31
  return v;            // lane 63 = full sum
}

// 32-block barrier, fence-free (all cross-block data via agent-scope atomics).
__device__ inline void gbar(int* cnt, int phase, int tid) {
  __syncthreads();
  if (tid == 0) {
    __hip_atomic_fetch_add(&cnt[phase], 1, __ATOMIC_RELEASE,
                           __HIP_MEMORY_SCOPE_AGENT);
    while (__hip_atomic_load(&cnt[phase], __ATOMIC_RELAXED,
                             __HIP_MEMORY_SCOPE_AGENT) < B)
      __builtin_amdgcn_s_sleep(2);
  }
  __syncthreads();
}

__global__ void __launch_bounds__(NT) fused14(Params p) {
  const int b = blockIdx.x, tid = threadIdx.x;
  const int lane = tid & 63, wid = tid >> 6;   // 16 waves

  __shared__ __align__(16) float slab[T * 11];   // scratch, then Iin [h][RS]
  __shared__ __align__(16) float gtab[T];        // 4KB
  __shared__ double dred2[60 * 17 + 4];          // combine partials (pad 17)
  __shared__ double dtot[60];
  __shared__ float stM[30], stI[30], Ms[100], Nl[100];

  float* swred = slab;          // [16][60] stats scratch (dead before S5)
  float* mpw   = slab + 1024;   // [16][100] M partials (dead before S5)

  // g[t] = (9(1-0.9^{T-t}) - 4(1-0.8^{T-t})) / T  (f32 closed form)
  {
    const float L2A = -0.15200309344504995f;   // log2(0.9)
    const float L2D = -0.32192809488736235f;   // log2(0.8)
    float m0 = (float)(T - tid);
    gtab[tid] = (9.0f * (1.0f - exp2f(m0 * L2A)) -
                 4.0f * (1.0f - exp2f(m0 * L2D))) * (1.0f / (float)T);
  }

  // parallel stats combine: P layout [ch][32]; ch x 16 workers, 2 loads each.
  auto combine = [&](double* P, int Q2) {
    for (int id = tid; id < Q2 * 16; id += NT) {
      int ch = id >> 4, i = id & 15;
      double s = __hip_atomic_load(&P[ch * 32 + i], __ATOMIC_RELAXED,
                                   __HIP_MEMORY_SCOPE_AGENT) +
                 __hip_atomic_load(&P[ch * 32 + 16 + i], __ATOMIC_RELAXED,
                                   __HIP_MEMORY_SCOPE_AGENT);
      dred2[ch * 17 + i] = s;
    }
    __syncthreads();
    if (tid < Q2) {
      double s = 0.0;
#pragma unroll
      for (int i = 0; i < 16; ++i) s += dred2[tid * 17 + i];
      dtot[tid] = s;
    }
    __syncthreads();
  };

  // ---------------- S1: embed (weights via uniform/scalar loads)
  float p1[H];
#pragma unroll
  for (int h = 0; h < H; ++h) p1[h] = p.b_ef[h];
  {
    const float* bp = p.beeg + (size_t)b * C * T;
#pragma unroll 8
    for (int c = 0; c < C; ++c) {
      float v = bp[(size_t)c * T + tid];
#pragma unroll
      for (int h = 0; h < H; ++h)
        p1[h] = fmaf(v, p.W_ef[h * C + c], p1[h]);   // wave-uniform weight
    }
  }
#pragma unroll
  for (int h = 0; h < H; ++h) {
    float r1 = wred63(p1[h]);
    float r2 = wred63(p1[h] * p1[h]);
    if (lane == 63) { swred[wid * 60 + h] = r1; swred[wid * 60 + 10 + h] = r2; }
  }
  __syncthreads();
  if (tid < 20) {
    float s = 0.f;
#pragma unroll
    for (int w = 0; w < 16; ++w) s += swred[w * 60 + tid];
    __hip_atomic_store(&p.P1[tid * 32 + b], (double)s, __ATOMIC_RELAXED,
                       __HIP_MEMORY_SCOPE_AGENT);
  }
  gbar(p.cnt, 0, tid);
  combine(p.P1, 20);
  if (tid < 10) {
    double mean = dtot[tid] * (1.0 / 32768.0);
    double var  = dtot[10 + tid] * (1.0 / 32768.0) - mean * mean;
    stM[tid] = (float)mean;
    stI[tid] = (float)(1.0 / sqrt(var + 1e-5));
  }
  __syncthreads();

  // ---------------- S2: x = tanh(bn(pre1)); qkv stats (accumulators only)
  float xa[H];
#pragma unroll
  for (int j = 0; j < H; ++j)
    xa[j] = tanhf(p.g_i[j] * (p1[j] - stM[j]) * stI[j] + p.be_i[j]);
#pragma unroll
  for (int h = 0; h < H; ++h) {
    float qa = 0.f, ka = 0.f, va = 0.f;
#pragma unroll
    for (int j = 0; j < H; ++j) {
      qa = fmaf(xa[j], p.Wq[h * H + j], qa);
      ka = fmaf(xa[j], p.Wk[h * H + j], ka);
      va = fmaf(xa[j], p.Wv[h * H + j], va);
    }
    float r1 = wred63(qa), r2 = wred63(qa * qa);
    float r3 = wred63(ka), r4 = wred63(ka * ka);
    float r5 = wred63(va), r6 = wred63(va * va);
    if (lane == 63) {
      swred[wid * 60 + h]      = r1; swred[wid * 60 + 30 + h] = r2;
      swred[wid * 60 + 10 + h] = r3; swred[wid * 60 + 40 + h] = r4;
      swred[wid * 60 + 20 + h] = r5; swred[wid * 60 + 50 + h] = r6;
    }
  }
  __syncthreads();
  if (tid < 60) {
    float s = 0.f;
#pragma unroll
    for (int w = 0; w < 16; ++w) s += swred[w * 60 + tid];
    __hip_atomic_store(&p.P2[tid * 32 + b], (double)s, __ATOMIC_RELAXED,
                       __HIP_MEMORY_SCOPE_AGENT);
  }
  gbar(p.cnt, 1, tid);
  combine(p.P2, 60);
  if (tid < 30) {
    double mean = dtot[tid] * (1.0 / 32768.0);
    double var  = dtot[30 + tid] * (1.0 / 32768.0) - mean * mean;
    stM[tid] = (float)mean;
    stI[tid] = (float)(1.0 / sqrt(var + 1e-5));
  }
  __syncthreads();

  // ---------------- S3: M = KV^T, single pass (one timestep per thread)
  {
    float kx[H], vx[H];
#pragma unroll
    for (int h = 0; h < H; ++h) {
      float ka = 0.f, va = 0.f;
#pragma unroll
      for (int j = 0; j < H; ++j) {
        ka = fmaf(xa[j], p.Wk[h * H + j], ka);
        va = fmaf(xa[j], p.Wv[h * H + j], va);
      }
      kx[h] = fmaxf(p.g_k[h] * (ka - stM[10 + h]) * stI[10 + h] + p.be_k[h], 0.f);
      vx[h] = tanhf(p.g_v[h] * (va - stM[20 + h]) * stI[20 + h] + p.be_v[h]);
    }
#pragma unroll
    for (int i = 0; i < H; ++i)
#pragma unroll
      for (int j = 0; j < H; ++j) {
        float r = wred63(kx[i] * vx[j]);
        if (lane == 63) mpw[wid * 100 + i * 10 + j] = r;
      }
  }
  __syncthreads();
  if (tid < 100) {
    float s = 0.f;
#pragma unroll
    for (int w = 0; w < 16; ++w) s += mpw[w * 100 + tid];
    Ms[tid] = s;
  }
  __syncthreads();

  // ---------------- S4: N = (M Wc^T)/H; recompute q; prec = q . N
  if (tid < 100) {
    int i = tid / 10, h = tid % 10;
    float a = 0.f;
#pragma unroll
    for (int j = 0; j < H; ++j) a = fmaf(Ms[i * 10 + j], p.Wc[h * H + j], a);
    Nl[tid] = a * 0.1f;
  }
  __syncthreads();
  float pca[H];
  {
    float qv[H];
#pragma unroll
    for (int h = 0; h < H; ++h) {
      float qa = 0.f;
#pragma unroll
      for (int j = 0; j < H; ++j) qa = fmaf(xa[j], p.Wq[h * H + j], qa);
      qv[h] = fmaxf(p.g_q[h] * (qa - stM[h]) * stI[h] + p.be_q[h], 0.f);
    }
#pragma unroll
    for (int h = 0; h < H; ++h) {
      float a = 0.f;
#pragma unroll
      for (int i = 0; i < H; ++i) a = fmaf(qv[i], Nl[i * 10 + h], a);
      pca[h] = a;
    }
  }
#pragma unroll
  for (int h = 0; h < H; ++h) {
    float r1 = wred63(pca[h]);
    float r2 = wred63(pca[h] * pca[h]);
    if (lane == 63) { swred[wid * 60 + h] = r1; swred[wid * 60 + 10 + h] = r2; }
  }
  __syncthreads();
  if (tid < 20) {
    float s = 0.f;
#pragma unroll
    for (int w = 0; w < 16; ++w) s += swred[w * 60 + tid];
    __hip_atomic_store(&p.P3[tid * 32 + b], (double)s, __ATOMIC_RELAXED,
                       __HIP_MEMORY_SCOPE_AGENT);
  }
  gbar(p.cnt, 2, tid);
  combine(p.P3, 20);
  if (tid < 10) {
    double mean = dtot[tid] * (1.0 / 32768.0);
    double var  = dtot[10 + tid] * (1.0 / 32768.0) - mean * mean;
    stM[tid] = (float)mean;
    stI[tid] = (float)(1.0 / sqrt(var + 1e-5));
  }
  __syncthreads();   // all slab-scratch reads done before S5 overwrites

  // ---------------- S5: bn+relu, Iin into LDS rows [h][RS]
  {
    float ca[H];
#pragma unroll
    for (int j = 0; j < H; ++j)
      ca[j] = fmaxf(p.g_c[j] * (pca[j] - stM[j]) * stI[j] + p.be_c[j], 0.f);
#pragma unroll
    for (int h = 0; h < H; ++h) {
      float a = 0.f;
#pragma unroll
      for (int j = 0; j < H; ++j) a = fmaf(ca[j], p.W_in[h * H + j], a);
      slab[h * RS + tid] = a;
    }
  }
  __syncthreads();

  // ---------------- S6: LSNN scan, wave 0 only; readlane + dual fma chains
  if (tid < 64) {
    // gtot closed form: .9^1024/.8^1024 underflow -> (5*1024 - 81 + 16)/1024
    const float gtot = 4.9365234375f;

    const int slot = lane < H ? lane : 0;   // inactive lanes broadcast row 0
    const float* row = slab + slot * RS;
    float wrf[H];                           // W_rec row (this lane's neuron)
#pragma unroll
    for (int j = 0; j < H; ++j)
      wrf[j] = (lane < H) ? p.W_rec[lane * H + j] : 0.f;

    float cur = 0.f, vm = 0.f, S = 0.f;
    float zf = 0.f;   // prev-step spike, per-lane float (lane j holds z_j)

    auto step = [&](float iin, float gt) {
      // i_jump = cur + iin + sum_j z_j*w_j as TWO parallel fma chains
      // (even/odd j) + one add: products exact (z in {0,1}); association
      // order change only (same class as R18's accepted reassociation).
      float zj[H];
#pragma unroll
      for (int j = 0; j < H; ++j)
        zj[j] = __int_as_float(
            __builtin_amdgcn_readlane(__float_as_int(zf), j));
      float acc0 = cur + iin;
      float acc1 = 0.f;
#pragma unroll
      for (int j = 0; j < H; j += 2) {
        acc0 = fmaf(zj[j],     wrf[j],     acc0);
        acc1 = fmaf(zj[j + 1], wrf[j + 1], acc1);
      }
      float acc = acc0 + acc1;
      float v_dec = fmaf(0.1f, acc - vm, vm);  // vm + 0.1*(i_jump - vm)
      cur = 0.8f * acc;                        // i_dec
      bool z = v_dec > 0.5f;
      vm = z ? 0.f : v_dec;
      zf = z ? 1.0f : 0.0f;
      S = fmaf(zf, gt, S);                     // exact: +gt or +0.0
    };

    float4 iA = *(const float4*)&row[0];
    float4 iB = *(const float4*)&row[4];
    float4 gA = *(const float4*)&gtab[0], gB = *(const float4*)&gtab[4];

    for (int t8 = 0; t8 < T - 8; t8 += 8) {
      float4 iN1 = *(const float4*)&row[t8 + 8];
      float4 iN2 = *(const float4*)&row[t8 + 12];
      float4 gN1 = *(const float4*)&gtab[t8 + 8];
      float4 gN2 = *(const float4*)&gtab[t8 + 12];
      step(iA.x, gA.x); step(iA.y, gA.y); step(iA.z, gA.z); step(iA.w, gA.w);
      step(iB.x, gB.x); step(iB.y, gB.y); step(iB.z, gB.z); step(iB.w, gB.w);
      iA = iN1; iB = iN2; gA = gN1; gB = gN2;
    }
    step(iA.x, gA.x); step(iA.y, gA.y); step(iA.z, gA.z); step(iA.w, gA.w);
    step(iB.x, gB.x); step(iB.y, gB.y); step(iB.z, gB.z); step(iB.w, gB.w);

    int li = lane < H ? lane : 0;
    float c0 = (lane < H) ? S * p.W_cls[li]     : 0.f;
    float c1 = (lane < H) ? S * p.W_cls[H + li] : 0.f;
    float r0 = wred63(c0), r1 = wred63(c1);
    if (lane == 63) {
      p.out[b * 2 + 0] = r0 + gtot * p.b_cls[0];
      p.out[b * 2 + 1] = r1 + gtot * p.b_cls[1];
    }
  }
}

extern "C" void kernel_launch(void* const* d_in, const int* in_sizes, int n_in,
                              void* d_out, int out_size, void* d_ws, size_t ws_size,
                              hipStream_t stream) {
  Params p;
  p.beeg  = (const float*)d_in[2];
  p.W_ef  = (const float*)d_in[4];
  p.b_ef  = (const float*)d_in[5];
  p.g_i   = (const float*)d_in[6];
  p.be_i  = (const float*)d_in[7];
  p.Wq    = (const float*)d_in[8];
  p.g_q   = (const float*)d_in[9];
  p.be_q  = (const float*)d_in[10];
  p.Wk    = (const float*)d_in[11];
  p.g_k   = (const float*)d_in[12];
  p.be_k  = (const float*)d_in[13];
  p.Wv    = (const float*)d_in[14];
  p.g_v   = (const float*)d_in[15];
  p.be_v  = (const float*)d_in[16];
  p.Wc    = (const float*)d_in[17];
  p.g_c   = (const float*)d_in[18];
  p.be_c  = (const float*)d_in[19];
  p.W_in  = (const float*)d_in[20];
  p.W_rec = (const float*)d_in[21];
  p.W_cls = (const float*)d_in[22];
  p.b_cls = (const float*)d_in[23];

  char* ws = (char*)d_ws;
  p.cnt = (int*)ws;                            // 3 counters, memset below
  p.P1  = (double*)(ws + 256);                 // [20][32] doubles
  p.P2  = (double*)(ws + 256 + 5120);          // [60][32] doubles
  p.P3  = (double*)(ws + 256 + 5120 + 15360);  // [20][32] doubles
  p.out = (float*)d_out;

  (void)hipMemsetAsync(d_ws, 0, 256, stream);  // zero barrier counters
  fused14<<<dim3(B), dim3(NT), 0, stream>>>(p);
}